// Round 1
// baseline (644.684 us; speedup 1.0000x reference)
//
#include <hip/hip_runtime.h>
#include <hip/hip_bf16.h>
#include <math.h>

#define NN 50000
#define CH 256          // feature width per node (both layers)
#define SCAN_BLOCK 1024

__device__ __forceinline__ float lrelu(float v) { return v > 0.f ? v : 0.2f * v; }
__device__ __forceinline__ float elu(float v)   { return v > 0.f ? v : __expf(v) - 1.f; }

// ---------------- GEMM1: x (n x 20) @ W (20 x 256) + b, for W_l1 and W_r1 ----------------
__global__ void gemm1_kernel(const float* __restrict__ x,
                             const float* __restrict__ Wl, const float* __restrict__ bl,
                             const float* __restrict__ Wr, const float* __restrict__ br,
                             float* __restrict__ xl, float* __restrict__ xr, int n) {
    __shared__ float xs[8][20];
    int n0 = blockIdx.x * 8;
    int tid = threadIdx.x;
    if (tid < 160) {
        int m = tid / 20, k = tid % 20;
        xs[m][k] = (n0 + m < n) ? x[(size_t)(n0 + m) * 20 + k] : 0.f;
    }
    __syncthreads();
    int c = tid;  // 256 output channels
    float al[8], ar[8];
#pragma unroll
    for (int m = 0; m < 8; ++m) { al[m] = 0.f; ar[m] = 0.f; }
#pragma unroll
    for (int k = 0; k < 20; ++k) {
        float wlv = Wl[k * 256 + c];
        float wrv = Wr[k * 256 + c];
#pragma unroll
        for (int m = 0; m < 8; ++m) {
            al[m] += xs[m][k] * wlv;
            ar[m] += xs[m][k] * wrv;
        }
    }
    float blv = bl[c], brv = br[c];
#pragma unroll
    for (int m = 0; m < 8; ++m) {
        if (n0 + m < n) {
            xl[(size_t)(n0 + m) * 256 + c] = al[m] + blv;
            xr[(size_t)(n0 + m) * 256 + c] = ar[m] + brv;
        }
    }
}

// ---------------- CSR build ----------------
__global__ void count_deg(const int* __restrict__ ei, int* __restrict__ deg, int e) {
    int t = blockIdx.x * blockDim.x + threadIdx.x;
    if (t < e) atomicAdd(&deg[ei[e + t]], 1);   // dst row
}

__global__ void scan_block_k(const int* __restrict__ deg, int* __restrict__ rowptr,
                             int* __restrict__ bsums, int n) {
    __shared__ int wsum[16];
    __shared__ int woff[17];
    int tid = threadIdx.x;
    int gi = blockIdx.x * SCAN_BLOCK + tid;
    int lane = tid & 63, wid = tid >> 6;
    int v = (gi < n) ? deg[gi] : 0;
    int incl = v;
#pragma unroll
    for (int d = 1; d < 64; d <<= 1) {
        int t = __shfl_up(incl, d, 64);
        if (lane >= d) incl += t;
    }
    if (lane == 63) wsum[wid] = incl;
    __syncthreads();
    if (tid < 16) {
        int s = wsum[tid];
#pragma unroll
        for (int d = 1; d < 16; d <<= 1) {
            int t = __shfl_up(s, d, 64);
            if (tid >= d) s += t;
        }
        woff[tid + 1] = s;
        if (tid == 0) woff[0] = 0;
    }
    __syncthreads();
    incl += woff[wid];
    if (gi < n) rowptr[gi + 1] = incl;
    if (tid == 0) bsums[blockIdx.x] = woff[16];
}

__global__ void scan_tops_k(int* bsums, int nb) {  // 1 block, 64 threads, nb <= 64
    int tid = threadIdx.x;
    int v = (tid < nb) ? bsums[tid] : 0;
    int incl = v;
#pragma unroll
    for (int d = 1; d < 64; d <<= 1) {
        int t = __shfl_up(incl, d, 64);
        if (tid >= d) incl += t;
    }
    if (tid < nb) bsums[tid] = incl - v;  // exclusive
}

__global__ void scan_fix_k(int* __restrict__ rowptr, int* __restrict__ cursor,
                           const int* __restrict__ deg, const int* __restrict__ bsums, int n) {
    int gi = blockIdx.x * SCAN_BLOCK + threadIdx.x;
    if (gi >= n) return;
    int off = bsums[blockIdx.x];
    int incl = rowptr[gi + 1] + off;
    rowptr[gi + 1] = incl;
    cursor[gi] = incl - deg[gi];
    if (gi == 0) rowptr[0] = 0;
}

__global__ void scatter_k(const int* __restrict__ ei, int* __restrict__ cursor,
                          int* __restrict__ csr, int e) {
    int t = blockIdx.x * blockDim.x + threadIdx.x;
    if (t >= e) return;
    int s = ei[t], d = ei[e + t];
    int idx = atomicAdd(&cursor[d], 1);
    csr[idx] = s;
}

// ---------------- Fused GATv2 layer 1: 4 heads x 64ch, online softmax + aggregate + bias + ELU ----------------
__global__ void fused_gat1(const float* __restrict__ xl, const float* __restrict__ xr,
                           const int* __restrict__ rowptr, const int* __restrict__ csr,
                           const float* __restrict__ att, const float* __restrict__ bias,
                           float* __restrict__ hout, int n) {
    int wid = threadIdx.x >> 6;
    int lane = threadIdx.x & 63;
    int i = blockIdx.x * 4 + wid;
    if (i >= n) return;
    float4 xr4 = ((const float4*)(xr + (size_t)i * CH))[lane];
    float4 a4  = ((const float4*)att)[lane];   // channels 4*lane..4*lane+3, head = lane>>4
    float m = -INFINITY, l = 0.f;
    float4 acc = make_float4(0.f, 0.f, 0.f, 0.f);
    int beg = rowptr[i], end = rowptr[i + 1];
    for (int e = beg - 1; e < end; ++e) {
        int s = (e < beg) ? i : csr[e];       // self-loop first
        float4 xl4 = ((const float4*)(xl + (size_t)s * CH))[lane];
        float p = lrelu(xl4.x + xr4.x) * a4.x + lrelu(xl4.y + xr4.y) * a4.y +
                  lrelu(xl4.z + xr4.z) * a4.z + lrelu(xl4.w + xr4.w) * a4.w;
        // reduce within 16-lane head group
        p += __shfl_xor(p, 1);
        p += __shfl_xor(p, 2);
        p += __shfl_xor(p, 4);
        p += __shfl_xor(p, 8);
        float mn = fmaxf(m, p);
        float sc = __expf(m - mn);
        float w  = __expf(p - mn);
        l = l * sc + w;
        acc.x = acc.x * sc + w * xl4.x;
        acc.y = acc.y * sc + w * xl4.y;
        acc.z = acc.z * sc + w * xl4.z;
        acc.w = acc.w * sc + w * xl4.w;
        m = mn;
    }
    float inv = 1.f / (l + 1e-16f);
    float4 b4 = ((const float4*)bias)[lane];
    float4 o;
    o.x = elu(acc.x * inv + b4.x);
    o.y = elu(acc.y * inv + b4.y);
    o.z = elu(acc.z * inv + b4.z);
    o.w = elu(acc.w * inv + b4.w);
    ((float4*)(hout + (size_t)i * CH))[lane] = o;
}

// ---------------- Fused GATv2 layer 2: 1 head x 256ch, + bias (no activation) ----------------
__global__ void fused_gat2(const float* __restrict__ xl, const float* __restrict__ xr,
                           const int* __restrict__ rowptr, const int* __restrict__ csr,
                           const float* __restrict__ att, const float* __restrict__ bias,
                           float* __restrict__ out, int n) {
    int wid = threadIdx.x >> 6;
    int lane = threadIdx.x & 63;
    int i = blockIdx.x * 4 + wid;
    if (i >= n) return;
    float4 xr4 = ((const float4*)(xr + (size_t)i * CH))[lane];
    float4 a4  = ((const float4*)att)[lane];
    float m = -INFINITY, l = 0.f;
    float4 acc = make_float4(0.f, 0.f, 0.f, 0.f);
    int beg = rowptr[i], end = rowptr[i + 1];
    for (int e = beg - 1; e < end; ++e) {
        int s = (e < beg) ? i : csr[e];
        float4 xl4 = ((const float4*)(xl + (size_t)s * CH))[lane];
        float p = lrelu(xl4.x + xr4.x) * a4.x + lrelu(xl4.y + xr4.y) * a4.y +
                  lrelu(xl4.z + xr4.z) * a4.z + lrelu(xl4.w + xr4.w) * a4.w;
        p += __shfl_xor(p, 1);
        p += __shfl_xor(p, 2);
        p += __shfl_xor(p, 4);
        p += __shfl_xor(p, 8);
        p += __shfl_xor(p, 16);
        p += __shfl_xor(p, 32);
        float mn = fmaxf(m, p);
        float sc = __expf(m - mn);
        float w  = __expf(p - mn);
        l = l * sc + w;
        acc.x = acc.x * sc + w * xl4.x;
        acc.y = acc.y * sc + w * xl4.y;
        acc.z = acc.z * sc + w * xl4.z;
        acc.w = acc.w * sc + w * xl4.w;
        m = mn;
    }
    float inv = 1.f / (l + 1e-16f);
    float4 b4 = ((const float4*)bias)[lane];
    float4 o;
    o.x = acc.x * inv + b4.x;
    o.y = acc.y * inv + b4.y;
    o.z = acc.z * inv + b4.z;
    o.w = acc.w * inv + b4.w;
    ((float4*)(out + (size_t)i * CH))[lane] = o;
}

// ---------------- GEMM2: h (M x 256) @ W (256 x 256) + b for two weight matrices ----------------
__global__ __launch_bounds__(256) void gemm256(const float* __restrict__ A,
                                               const float* __restrict__ Wa, const float* __restrict__ ba,
                                               const float* __restrict__ Wb, const float* __restrict__ bb,
                                               float* __restrict__ Ca, float* __restrict__ Cb, int M) {
    const float* W    = blockIdx.z ? Wb : Wa;
    const float* bias = blockIdx.z ? bb : ba;
    float* C          = blockIdx.z ? Cb : Ca;
    __shared__ float As[16][64];  // [k][m]
    __shared__ float Bs[16][64];  // [k][n]
    int m0 = blockIdx.x * 64, n0 = blockIdx.y * 64;
    int tid = threadIdx.x;
    int tx = tid & 15, ty = tid >> 4;
    float c[4][4];
#pragma unroll
    for (int i = 0; i < 4; ++i)
#pragma unroll
        for (int j = 0; j < 4; ++j) c[i][j] = 0.f;

    int am = tid >> 2, ak = (tid & 3) * 4;
    int bk = tid >> 4, bn = (tid & 15) * 4;
    for (int kb = 0; kb < 256; kb += 16) {
        float4 av = make_float4(0.f, 0.f, 0.f, 0.f);
        if (m0 + am < M) av = *(const float4*)(A + (size_t)(m0 + am) * 256 + kb + ak);
        As[ak + 0][am] = av.x;
        As[ak + 1][am] = av.y;
        As[ak + 2][am] = av.z;
        As[ak + 3][am] = av.w;
        float4 bv = *(const float4*)(W + (size_t)(kb + bk) * 256 + n0 + bn);
        *(float4*)&Bs[bk][bn] = bv;
        __syncthreads();
#pragma unroll
        for (int k = 0; k < 16; ++k) {
            float4 a4 = *(const float4*)&As[k][ty * 4];
            float4 b4 = *(const float4*)&Bs[k][tx * 4];
            c[0][0] += a4.x * b4.x; c[0][1] += a4.x * b4.y; c[0][2] += a4.x * b4.z; c[0][3] += a4.x * b4.w;
            c[1][0] += a4.y * b4.x; c[1][1] += a4.y * b4.y; c[1][2] += a4.y * b4.z; c[1][3] += a4.y * b4.w;
            c[2][0] += a4.z * b4.x; c[2][1] += a4.z * b4.y; c[2][2] += a4.z * b4.z; c[2][3] += a4.z * b4.w;
            c[3][0] += a4.w * b4.x; c[3][1] += a4.w * b4.y; c[3][2] += a4.w * b4.z; c[3][3] += a4.w * b4.w;
        }
        __syncthreads();
    }
    float4 bv4 = *(const float4*)(bias + n0 + tx * 4);
#pragma unroll
    for (int i = 0; i < 4; ++i) {
        int row = m0 + ty * 4 + i;
        if (row < M) {
            float4 o = make_float4(c[i][0] + bv4.x, c[i][1] + bv4.y, c[i][2] + bv4.z, c[i][3] + bv4.w);
            *(float4*)(C + (size_t)row * 256 + n0 + tx * 4) = o;
        }
    }
}

extern "C" void kernel_launch(void* const* d_in, const int* in_sizes, int n_in,
                              void* d_out, int out_size, void* d_ws, size_t ws_size,
                              hipStream_t stream) {
    const float* x    = (const float*)d_in[0];
    const int*   ei   = (const int*)d_in[1];
    const float* Wl1  = (const float*)d_in[2];
    const float* bl1  = (const float*)d_in[3];
    const float* Wr1  = (const float*)d_in[4];
    const float* br1  = (const float*)d_in[5];
    const float* att1 = (const float*)d_in[6];
    const float* bias1= (const float*)d_in[7];
    const float* Wl2  = (const float*)d_in[8];
    const float* bl2  = (const float*)d_in[9];
    const float* Wr2  = (const float*)d_in[10];
    const float* br2  = (const float*)d_in[11];
    const float* att2 = (const float*)d_in[12];
    const float* bias2= (const float*)d_in[13];

    int n = in_sizes[0] / 20;
    int e = in_sizes[1] / 2;
    float* out = (float*)d_out;

    float* buf0 = (float*)d_ws;                     // xl1 / xl2 : n*256
    float* buf1 = buf0 + (size_t)n * CH;            // xr1 / xr2 : n*256
    int* deg    = (int*)(buf1 + (size_t)n * CH);    // n
    int* rowptr = deg + n;                          // n+1
    int* cursor = rowptr + n + 1;                   // n
    int* bsums  = cursor + n;                       // 64
    int* csr    = bsums + 64;                       // e

    hipMemsetAsync(deg, 0, (size_t)n * sizeof(int), stream);

    // layer 1 linear transforms
    gemm1_kernel<<<(n + 7) / 8, 256, 0, stream>>>(x, Wl1, bl1, Wr1, br1, buf0, buf1, n);

    // CSR build (dst-grouped); self-loops handled inside fused kernels
    count_deg<<<(e + 255) / 256, 256, 0, stream>>>(ei, deg, e);
    int nb = (n + SCAN_BLOCK - 1) / SCAN_BLOCK;
    scan_block_k<<<nb, SCAN_BLOCK, 0, stream>>>(deg, rowptr, bsums, n);
    scan_tops_k<<<1, 64, 0, stream>>>(bsums, nb);
    scan_fix_k<<<nb, SCAN_BLOCK, 0, stream>>>(rowptr, cursor, deg, bsums, n);
    scatter_k<<<(e + 255) / 256, 256, 0, stream>>>(ei, cursor, csr, e);

    // layer 1 attention + aggregate + bias + ELU  -> h stored in d_out (scratch)
    fused_gat1<<<(n + 3) / 4, 256, 0, stream>>>(buf0, buf1, rowptr, csr, att1, bias1, out, n);

    // layer 2 linear transforms: xl2 -> buf0, xr2 -> buf1
    gemm256<<<dim3((n + 63) / 64, 4, 2), 256, 0, stream>>>(out, Wl2, bl2, Wr2, br2, buf0, buf1, n);

    // layer 2 attention + aggregate + bias -> final output
    fused_gat2<<<(n + 3) / 4, 256, 0, stream>>>(buf0, buf1, rowptr, csr, att2, bias2, out, n);
}

// Round 2
// 512.553 us; speedup vs baseline: 1.2578x; 1.2578x over previous
//
#include <hip/hip_runtime.h>
#include <hip/hip_bf16.h>
#include <math.h>

#define CH 256
#define SCAN_BLOCK 1024

typedef short bf16x8 __attribute__((ext_vector_type(8)));
typedef float f32x4 __attribute__((ext_vector_type(4)));

__device__ __forceinline__ float lrelu(float v) { return v > 0.f ? v : 0.2f * v; }
__device__ __forceinline__ float elu(float v)   { return v > 0.f ? v : __expf(v) - 1.f; }

__device__ __forceinline__ unsigned short f2bf(float f) {
    unsigned u = __float_as_uint(f);
    return (unsigned short)((u + 0x7fffu + ((u >> 16) & 1u)) >> 16);
}
// load 4 consecutive bf16 channels for this lane (8 bytes)
__device__ __forceinline__ float4 ldbf4(const unsigned short* rowbase, int lane) {
    uint2 u = ((const uint2*)rowbase)[lane];
    return make_float4(__uint_as_float(u.x << 16), __uint_as_float(u.x & 0xffff0000u),
                       __uint_as_float(u.y << 16), __uint_as_float(u.y & 0xffff0000u));
}
__device__ __forceinline__ void stbf4(unsigned short* rowbase, int lane, float4 v) {
    uint2 u;
    u.x = (unsigned)f2bf(v.x) | ((unsigned)f2bf(v.y) << 16);
    u.y = (unsigned)f2bf(v.z) | ((unsigned)f2bf(v.w) << 16);
    ((uint2*)rowbase)[lane] = u;
}

// ---------------- GEMM1: x (n x 20) @ W (20 x 256) + b -> bf16 xl, xr ----------------
__global__ void gemm1_kernel(const float* __restrict__ x,
                             const float* __restrict__ Wl, const float* __restrict__ bl,
                             const float* __restrict__ Wr, const float* __restrict__ br,
                             unsigned short* __restrict__ xl, unsigned short* __restrict__ xr, int n) {
    __shared__ float xs[8][20];
    int n0 = blockIdx.x * 8;
    int tid = threadIdx.x;
    if (tid < 160) {
        int m = tid / 20, k = tid % 20;
        xs[m][k] = (n0 + m < n) ? x[(size_t)(n0 + m) * 20 + k] : 0.f;
    }
    __syncthreads();
    int c = tid;
    float al[8], ar[8];
#pragma unroll
    for (int m = 0; m < 8; ++m) { al[m] = 0.f; ar[m] = 0.f; }
#pragma unroll
    for (int k = 0; k < 20; ++k) {
        float wlv = Wl[k * 256 + c];
        float wrv = Wr[k * 256 + c];
#pragma unroll
        for (int m = 0; m < 8; ++m) {
            al[m] += xs[m][k] * wlv;
            ar[m] += xs[m][k] * wrv;
        }
    }
    float blv = bl[c], brv = br[c];
#pragma unroll
    for (int m = 0; m < 8; ++m) {
        if (n0 + m < n) {
            xl[(size_t)(n0 + m) * 256 + c] = f2bf(al[m] + blv);
            xr[(size_t)(n0 + m) * 256 + c] = f2bf(ar[m] + brv);
        }
    }
}

// ---------------- CSR build ----------------
__global__ void count_deg(const int* __restrict__ ei, int* __restrict__ deg, int e) {
    int t = blockIdx.x * blockDim.x + threadIdx.x;
    if (t < e) atomicAdd(&deg[ei[e + t]], 1);
}

__global__ void scan_block_k(const int* __restrict__ deg, int* __restrict__ rowptr,
                             int* __restrict__ bsums, int n) {
    __shared__ int wsum[16];
    __shared__ int woff[17];
    int tid = threadIdx.x;
    int gi = blockIdx.x * SCAN_BLOCK + tid;
    int lane = tid & 63, wid = tid >> 6;
    int v = (gi < n) ? deg[gi] : 0;
    int incl = v;
#pragma unroll
    for (int d = 1; d < 64; d <<= 1) {
        int t = __shfl_up(incl, d, 64);
        if (lane >= d) incl += t;
    }
    if (lane == 63) wsum[wid] = incl;
    __syncthreads();
    if (tid < 16) {
        int s = wsum[tid];
#pragma unroll
        for (int d = 1; d < 16; d <<= 1) {
            int t = __shfl_up(s, d, 64);
            if (tid >= d) s += t;
        }
        woff[tid + 1] = s;
        if (tid == 0) woff[0] = 0;
    }
    __syncthreads();
    incl += woff[wid];
    if (gi < n) rowptr[gi + 1] = incl;
    if (tid == 0) bsums[blockIdx.x] = woff[16];
}

__global__ void scan_tops_k(int* bsums, int nb) {
    int tid = threadIdx.x;
    int v = (tid < nb) ? bsums[tid] : 0;
    int incl = v;
#pragma unroll
    for (int d = 1; d < 64; d <<= 1) {
        int t = __shfl_up(incl, d, 64);
        if (tid >= d) incl += t;
    }
    if (tid < nb) bsums[tid] = incl - v;
}

__global__ void scan_fix_k(int* __restrict__ rowptr, int* __restrict__ cursor,
                           const int* __restrict__ deg, const int* __restrict__ bsums, int n) {
    int gi = blockIdx.x * SCAN_BLOCK + threadIdx.x;
    if (gi >= n) return;
    int off = bsums[blockIdx.x];
    int incl = rowptr[gi + 1] + off;
    rowptr[gi + 1] = incl;
    cursor[gi] = incl - deg[gi];
    if (gi == 0) rowptr[0] = 0;
}

__global__ void scatter_k(const int* __restrict__ ei, int* __restrict__ cursor,
                          int* __restrict__ csr, int e) {
    int t = blockIdx.x * blockDim.x + threadIdx.x;
    if (t >= e) return;
    int s = ei[t], d = ei[e + t];
    int idx = atomicAdd(&cursor[d], 1);
    csr[idx] = s;
}

// ---------------- Fused GATv2 layer 1 (bf16 in, bf16 out) ----------------
__global__ void fused_gat1(const unsigned short* __restrict__ xl, const unsigned short* __restrict__ xr,
                           const int* __restrict__ rowptr, const int* __restrict__ csr,
                           const float* __restrict__ att, const float* __restrict__ bias,
                           unsigned short* __restrict__ hout, int n) {
    int wid = threadIdx.x >> 6;
    int lane = threadIdx.x & 63;
    int i = blockIdx.x * 4 + wid;
    if (i >= n) return;
    float4 xr4 = ldbf4(xr + (size_t)i * CH, lane);
    float4 a4  = ((const float4*)att)[lane];
    float m = -INFINITY, l = 0.f;
    float4 acc = make_float4(0.f, 0.f, 0.f, 0.f);
    int beg = rowptr[i], end = rowptr[i + 1];
    for (int e = beg - 1; e < end; ++e) {
        int s = (e < beg) ? i : csr[e];
        float4 xl4 = ldbf4(xl + (size_t)s * CH, lane);
        float p = lrelu(xl4.x + xr4.x) * a4.x + lrelu(xl4.y + xr4.y) * a4.y +
                  lrelu(xl4.z + xr4.z) * a4.z + lrelu(xl4.w + xr4.w) * a4.w;
        p += __shfl_xor(p, 1);
        p += __shfl_xor(p, 2);
        p += __shfl_xor(p, 4);
        p += __shfl_xor(p, 8);
        float mn = fmaxf(m, p);
        float sc = __expf(m - mn);
        float w  = __expf(p - mn);
        l = l * sc + w;
        acc.x = acc.x * sc + w * xl4.x;
        acc.y = acc.y * sc + w * xl4.y;
        acc.z = acc.z * sc + w * xl4.z;
        acc.w = acc.w * sc + w * xl4.w;
        m = mn;
    }
    float inv = 1.f / (l + 1e-16f);
    float4 b4 = ((const float4*)bias)[lane];
    float4 o;
    o.x = elu(acc.x * inv + b4.x);
    o.y = elu(acc.y * inv + b4.y);
    o.z = elu(acc.z * inv + b4.z);
    o.w = elu(acc.w * inv + b4.w);
    stbf4(hout + (size_t)i * CH, lane, o);
}

// ---------------- Fused GATv2 layer 2 (bf16 in, fp32 out) ----------------
__global__ void fused_gat2(const unsigned short* __restrict__ xl, const unsigned short* __restrict__ xr,
                           const int* __restrict__ rowptr, const int* __restrict__ csr,
                           const float* __restrict__ att, const float* __restrict__ bias,
                           float* __restrict__ out, int n) {
    int wid = threadIdx.x >> 6;
    int lane = threadIdx.x & 63;
    int i = blockIdx.x * 4 + wid;
    if (i >= n) return;
    float4 xr4 = ldbf4(xr + (size_t)i * CH, lane);
    float4 a4  = ((const float4*)att)[lane];
    float m = -INFINITY, l = 0.f;
    float4 acc = make_float4(0.f, 0.f, 0.f, 0.f);
    int beg = rowptr[i], end = rowptr[i + 1];
    for (int e = beg - 1; e < end; ++e) {
        int s = (e < beg) ? i : csr[e];
        float4 xl4 = ldbf4(xl + (size_t)s * CH, lane);
        float p = lrelu(xl4.x + xr4.x) * a4.x + lrelu(xl4.y + xr4.y) * a4.y +
                  lrelu(xl4.z + xr4.z) * a4.z + lrelu(xl4.w + xr4.w) * a4.w;
        p += __shfl_xor(p, 1);
        p += __shfl_xor(p, 2);
        p += __shfl_xor(p, 4);
        p += __shfl_xor(p, 8);
        p += __shfl_xor(p, 16);
        p += __shfl_xor(p, 32);
        float mn = fmaxf(m, p);
        float sc = __expf(m - mn);
        float w  = __expf(p - mn);
        l = l * sc + w;
        acc.x = acc.x * sc + w * xl4.x;
        acc.y = acc.y * sc + w * xl4.y;
        acc.z = acc.z * sc + w * xl4.z;
        acc.w = acc.w * sc + w * xl4.w;
        m = mn;
    }
    float inv = 1.f / (l + 1e-16f);
    float4 b4 = ((const float4*)bias)[lane];
    float4 o;
    o.x = acc.x * inv + b4.x;
    o.y = acc.y * inv + b4.y;
    o.z = acc.z * inv + b4.z;
    o.w = acc.w * inv + b4.w;
    ((float4*)(out + (size_t)i * CH))[lane] = o;
}

// ---------------- transpose+convert layer2 weights: Wt[z][n][k] bf16 ----------------
__global__ void wconv(const float* __restrict__ Wl2, const float* __restrict__ Wr2,
                      unsigned short* __restrict__ Wt) {
    int t = blockIdx.x * 256 + threadIdx.x;   // 0..131071
    int z = t >> 16;
    int idx = t & 65535;
    int k = idx >> 8, nn = idx & 255;
    const float* W = z ? Wr2 : Wl2;
    Wt[z * 65536 + nn * 256 + k] = f2bf(W[k * 256 + nn]);
}

// ---------------- GEMM2 MFMA: h (M x 256 bf16) @ Wt^T + b -> bf16, two weight mats ----------------
#define LDK 40
__global__ __launch_bounds__(256) void gemm_mfma(
        const unsigned short* __restrict__ A,   // M x 256 bf16
        const unsigned short* __restrict__ Wt,  // 2 x 256(n) x 256(k) bf16
        const float* __restrict__ ba, const float* __restrict__ bb,
        unsigned short* __restrict__ Ca, unsigned short* __restrict__ Cb, int M) {
    const unsigned short* Wz = Wt + (size_t)blockIdx.z * 65536;
    const float* bias = blockIdx.z ? bb : ba;
    unsigned short* C = blockIdx.z ? Cb : Ca;

    __shared__ unsigned short As[128 * LDK];
    __shared__ unsigned short Bs[128 * LDK];

    int m0 = blockIdx.x * 128, n0 = blockIdx.y * 128;
    int tid = threadIdx.x;
    int lane = tid & 63, wid = tid >> 6;
    int wm = wid & 1, wn = wid >> 1;
    int q = lane >> 4, l15 = lane & 15;

    f32x4 acc[4][4];
#pragma unroll
    for (int i = 0; i < 4; ++i)
#pragma unroll
        for (int j = 0; j < 4; ++j) acc[i][j] = (f32x4){0.f, 0.f, 0.f, 0.f};

    int r = tid >> 2;            // 0..63
    int c8 = (tid & 3) * 8;      // 0,8,16,24
    const uint4 zero4 = make_uint4(0, 0, 0, 0);

    for (int kb = 0; kb < 8; ++kb) {
        int k0 = kb * 32;
        int ra = m0 + r, rb = m0 + r + 64;
        uint4 va0 = (ra < M) ? *(const uint4*)(A + (size_t)ra * 256 + k0 + c8) : zero4;
        uint4 va1 = (rb < M) ? *(const uint4*)(A + (size_t)rb * 256 + k0 + c8) : zero4;
        uint4 vb0 = *(const uint4*)(Wz + (size_t)(n0 + r) * 256 + k0 + c8);
        uint4 vb1 = *(const uint4*)(Wz + (size_t)(n0 + r + 64) * 256 + k0 + c8);
        __syncthreads();
        *(uint4*)&As[r * LDK + c8] = va0;
        *(uint4*)&As[(r + 64) * LDK + c8] = va1;
        *(uint4*)&Bs[r * LDK + c8] = vb0;
        *(uint4*)&Bs[(r + 64) * LDK + c8] = vb1;
        __syncthreads();

        bf16x8 af[4], bfr[4];
#pragma unroll
        for (int f = 0; f < 4; ++f)
            af[f] = *(const bf16x8*)&As[(wm * 64 + f * 16 + l15) * LDK + q * 8];
#pragma unroll
        for (int f = 0; f < 4; ++f)
            bfr[f] = *(const bf16x8*)&Bs[(wn * 64 + f * 16 + l15) * LDK + q * 8];
#pragma unroll
        for (int i = 0; i < 4; ++i)
#pragma unroll
            for (int j = 0; j < 4; ++j)
                acc[i][j] = __builtin_amdgcn_mfma_f32_16x16x32_bf16(af[i], bfr[j], acc[i][j], 0, 0, 0);
    }

#pragma unroll
    for (int j = 0; j < 4; ++j) {
        int gcol = n0 + wn * 64 + j * 16 + l15;
        float bcol = bias[gcol];
#pragma unroll
        for (int i = 0; i < 4; ++i) {
            int row = m0 + wm * 64 + i * 16 + q * 4;
#pragma unroll
            for (int rr = 0; rr < 4; ++rr) {
                int grow = row + rr;
                if (grow < M)
                    C[(size_t)grow * 256 + gcol] = f2bf(acc[i][j][rr] + bcol);
            }
        }
    }
}

extern "C" void kernel_launch(void* const* d_in, const int* in_sizes, int n_in,
                              void* d_out, int out_size, void* d_ws, size_t ws_size,
                              hipStream_t stream) {
    const float* x    = (const float*)d_in[0];
    const int*   ei   = (const int*)d_in[1];
    const float* Wl1  = (const float*)d_in[2];
    const float* bl1  = (const float*)d_in[3];
    const float* Wr1  = (const float*)d_in[4];
    const float* br1  = (const float*)d_in[5];
    const float* att1 = (const float*)d_in[6];
    const float* bias1= (const float*)d_in[7];
    const float* Wl2  = (const float*)d_in[8];
    const float* bl2  = (const float*)d_in[9];
    const float* Wr2  = (const float*)d_in[10];
    const float* br2  = (const float*)d_in[11];
    const float* att2 = (const float*)d_in[12];
    const float* bias2= (const float*)d_in[13];

    int n = in_sizes[0] / 20;
    int e = in_sizes[1] / 2;
    float* out = (float*)d_out;
    size_t nch = (size_t)n * CH;

    unsigned short* buf0 = (unsigned short*)d_ws;       // xl (bf16)
    unsigned short* buf1 = buf0 + nch;                  // xr (bf16)
    unsigned short* hbuf = buf1 + nch;                  // h  (bf16)
    unsigned short* wt2  = hbuf + nch;                  // 2*256*256 bf16
    int* deg    = (int*)(wt2 + 2 * 65536);
    int* rowptr = deg + n;
    int* cursor = rowptr + n + 1;
    int* bsums  = cursor + n;
    int* csr    = bsums + 64;

    hipMemsetAsync(deg, 0, (size_t)n * sizeof(int), stream);

    gemm1_kernel<<<(n + 7) / 8, 256, 0, stream>>>(x, Wl1, bl1, Wr1, br1, buf0, buf1, n);

    count_deg<<<(e + 255) / 256, 256, 0, stream>>>(ei, deg, e);
    int nb = (n + SCAN_BLOCK - 1) / SCAN_BLOCK;
    scan_block_k<<<nb, SCAN_BLOCK, 0, stream>>>(deg, rowptr, bsums, n);
    scan_tops_k<<<1, 64, 0, stream>>>(bsums, nb);
    scan_fix_k<<<nb, SCAN_BLOCK, 0, stream>>>(rowptr, cursor, deg, bsums, n);
    scatter_k<<<(e + 255) / 256, 256, 0, stream>>>(ei, cursor, csr, e);

    wconv<<<512, 256, 0, stream>>>(Wl2, Wr2, wt2);

    fused_gat1<<<(n + 3) / 4, 256, 0, stream>>>(buf0, buf1, rowptr, csr, att1, bias1, hbuf, n);

    gemm_mfma<<<dim3((n + 127) / 128, 2, 2), 256, 0, stream>>>(hbuf, wt2, bl2, br2, buf0, buf1, n);

    fused_gat2<<<(n + 3) / 4, 256, 0, stream>>>(buf0, buf1, rowptr, csr, att2, bias2, out, n);
}

// Round 3
// 326.677 us; speedup vs baseline: 1.9735x; 1.5690x over previous
//
#include <hip/hip_runtime.h>
#include <hip/hip_bf16.h>
#include <math.h>

#define CH 256
#define SCAN_BLOCK 1024

typedef short bf16x8 __attribute__((ext_vector_type(8)));
typedef float f32x4 __attribute__((ext_vector_type(4)));

__device__ __forceinline__ float lrelu(float v) { return fmaxf(v, 0.2f * v); }
__device__ __forceinline__ float elu(float v)   { return v > 0.f ? v : __expf(v) - 1.f; }

__device__ __forceinline__ unsigned short f2bf(float f) {
    unsigned u = __float_as_uint(f);
    return (unsigned short)((u + 0x7fffu + ((u >> 16) & 1u)) >> 16);
}
__device__ __forceinline__ float4 ldbf4(const unsigned short* rowbase, int lane) {
    uint2 u = ((const uint2*)rowbase)[lane];
    return make_float4(__uint_as_float(u.x << 16), __uint_as_float(u.x & 0xffff0000u),
                       __uint_as_float(u.y << 16), __uint_as_float(u.y & 0xffff0000u));
}
__device__ __forceinline__ void stbf4(unsigned short* rowbase, int lane, float4 v) {
    uint2 u;
    u.x = (unsigned)f2bf(v.x) | ((unsigned)f2bf(v.y) << 16);
    u.y = (unsigned)f2bf(v.z) | ((unsigned)f2bf(v.w) << 16);
    ((uint2*)rowbase)[lane] = u;
}

// ---------------- GEMM1: x (n x 20) @ W (20 x 256) + b -> bf16 xl, xr ----------------
// 64 rows/block; W column held in 40 registers (read once per block, not per 8 rows).
__global__ __launch_bounds__(256) void gemm1_kernel(const float* __restrict__ x,
                             const float* __restrict__ Wl, const float* __restrict__ bl,
                             const float* __restrict__ Wr, const float* __restrict__ br,
                             unsigned short* __restrict__ xl, unsigned short* __restrict__ xr, int n) {
    __shared__ float xs[64][20];
    int n0 = blockIdx.x * 64;
    int tid = threadIdx.x;
    for (int i = tid; i < 64 * 20; i += 256) {
        int m = i / 20, k = i % 20;
        int row = n0 + m;
        xs[m][k] = (row < n) ? x[(size_t)row * 20 + k] : 0.f;
    }
    int c = tid;
    float wl[20], wr[20];
#pragma unroll
    for (int k = 0; k < 20; ++k) { wl[k] = Wl[k * 256 + c]; wr[k] = Wr[k * 256 + c]; }
    float blv = bl[c], brv = br[c];
    __syncthreads();
#pragma unroll 1
    for (int g = 0; g < 8; ++g) {
        int base = g * 8;
        float al[8], ar[8];
#pragma unroll
        for (int m = 0; m < 8; ++m) { al[m] = blv; ar[m] = brv; }
#pragma unroll
        for (int k = 0; k < 20; ++k) {
            float wlv = wl[k], wrv = wr[k];
#pragma unroll
            for (int m = 0; m < 8; ++m) {
                float xv = xs[base + m][k];
                al[m] += xv * wlv;
                ar[m] += xv * wrv;
            }
        }
#pragma unroll
        for (int m = 0; m < 8; ++m) {
            int row = n0 + base + m;
            if (row < n) {
                xl[(size_t)row * 256 + c] = f2bf(al[m]);
                xr[(size_t)row * 256 + c] = f2bf(ar[m]);
            }
        }
    }
}

// ---------------- CSR build ----------------
__global__ void count_deg(const int* __restrict__ ei, int* __restrict__ deg, int e) {
    int t = blockIdx.x * blockDim.x + threadIdx.x;
    if (t < e) atomicAdd(&deg[ei[e + t]], 1);
}

__global__ void scan_block_k(const int* __restrict__ deg, int* __restrict__ rowptr,
                             int* __restrict__ bsums, int n) {
    __shared__ int wsum[16];
    __shared__ int woff[17];
    int tid = threadIdx.x;
    int gi = blockIdx.x * SCAN_BLOCK + tid;
    int lane = tid & 63, wid = tid >> 6;
    int v = (gi < n) ? deg[gi] : 0;
    int incl = v;
#pragma unroll
    for (int d = 1; d < 64; d <<= 1) {
        int t = __shfl_up(incl, d, 64);
        if (lane >= d) incl += t;
    }
    if (lane == 63) wsum[wid] = incl;
    __syncthreads();
    if (tid < 16) {
        int s = wsum[tid];
#pragma unroll
        for (int d = 1; d < 16; d <<= 1) {
            int t = __shfl_up(s, d, 64);
            if (tid >= d) s += t;
        }
        woff[tid + 1] = s;
        if (tid == 0) woff[0] = 0;
    }
    __syncthreads();
    incl += woff[wid];
    if (gi < n) rowptr[gi + 1] = incl;
    if (tid == 0) bsums[blockIdx.x] = woff[16];
}

__global__ void scan_tops_k(int* bsums, int nb) {
    int tid = threadIdx.x;
    int v = (tid < nb) ? bsums[tid] : 0;
    int incl = v;
#pragma unroll
    for (int d = 1; d < 64; d <<= 1) {
        int t = __shfl_up(incl, d, 64);
        if (tid >= d) incl += t;
    }
    if (tid < nb) bsums[tid] = incl - v;
}

__global__ void scan_fix_k(int* __restrict__ rowptr, int* __restrict__ cursor,
                           const int* __restrict__ deg, const int* __restrict__ bsums, int n) {
    int gi = blockIdx.x * SCAN_BLOCK + threadIdx.x;
    if (gi >= n) return;
    int off = bsums[blockIdx.x];
    int incl = rowptr[gi + 1] + off;
    rowptr[gi + 1] = incl;
    cursor[gi] = incl - deg[gi];
    if (gi == 0) rowptr[0] = 0;
}

__global__ void scatter_k(const int* __restrict__ ei, int* __restrict__ cursor,
                          int* __restrict__ csr, int e) {
    int t = blockIdx.x * blockDim.x + threadIdx.x;
    if (t >= e) return;
    int s = ei[t], d = ei[e + t];
    int idx = atomicAdd(&cursor[d], 1);
    csr[idx] = s;
}

// ---------------- Fused GATv2 layer 1 (bf16 in, bf16 out), 4-edge batched ----------------
__global__ void fused_gat1(const unsigned short* __restrict__ xl, const unsigned short* __restrict__ xr,
                           const int* __restrict__ rowptr, const int* __restrict__ csr,
                           const float* __restrict__ att, const float* __restrict__ bias,
                           unsigned short* __restrict__ hout, int n) {
    int wid = threadIdx.x >> 6;
    int lane = threadIdx.x & 63;
    int i = blockIdx.x * 4 + wid;
    if (i >= n) return;
    float4 xr4 = ldbf4(xr + (size_t)i * CH, lane);
    float4 a4  = ((const float4*)att)[lane];
    // self-loop first (w = exp(0) = 1 after normalizing to its own max)
    float4 xli = ldbf4(xl + (size_t)i * CH, lane);
    float ps = lrelu(xli.x + xr4.x) * a4.x + lrelu(xli.y + xr4.y) * a4.y +
               lrelu(xli.z + xr4.z) * a4.z + lrelu(xli.w + xr4.w) * a4.w;
    ps += __shfl_xor(ps, 1); ps += __shfl_xor(ps, 2);
    ps += __shfl_xor(ps, 4); ps += __shfl_xor(ps, 8);
    float m = ps, l = 1.f;
    float4 acc = xli;
    int beg = rowptr[i], end = rowptr[i + 1];
    for (int e = beg; e < end; e += 4) {
        int cnt = end - e;
        int s0 = csr[e];
        int s1 = (cnt > 1) ? csr[e + 1] : s0;
        int s2 = (cnt > 2) ? csr[e + 2] : s0;
        int s3 = (cnt > 3) ? csr[e + 3] : s0;
        float4 r0 = ldbf4(xl + (size_t)s0 * CH, lane);
        float4 r1 = ldbf4(xl + (size_t)s1 * CH, lane);
        float4 r2 = ldbf4(xl + (size_t)s2 * CH, lane);
        float4 r3 = ldbf4(xl + (size_t)s3 * CH, lane);
        float p0 = lrelu(r0.x + xr4.x) * a4.x + lrelu(r0.y + xr4.y) * a4.y +
                   lrelu(r0.z + xr4.z) * a4.z + lrelu(r0.w + xr4.w) * a4.w;
        float p1 = lrelu(r1.x + xr4.x) * a4.x + lrelu(r1.y + xr4.y) * a4.y +
                   lrelu(r1.z + xr4.z) * a4.z + lrelu(r1.w + xr4.w) * a4.w;
        float p2 = lrelu(r2.x + xr4.x) * a4.x + lrelu(r2.y + xr4.y) * a4.y +
                   lrelu(r2.z + xr4.z) * a4.z + lrelu(r2.w + xr4.w) * a4.w;
        float p3 = lrelu(r3.x + xr4.x) * a4.x + lrelu(r3.y + xr4.y) * a4.y +
                   lrelu(r3.z + xr4.z) * a4.z + lrelu(r3.w + xr4.w) * a4.w;
        p0 += __shfl_xor(p0, 1); p1 += __shfl_xor(p1, 1); p2 += __shfl_xor(p2, 1); p3 += __shfl_xor(p3, 1);
        p0 += __shfl_xor(p0, 2); p1 += __shfl_xor(p1, 2); p2 += __shfl_xor(p2, 2); p3 += __shfl_xor(p3, 2);
        p0 += __shfl_xor(p0, 4); p1 += __shfl_xor(p1, 4); p2 += __shfl_xor(p2, 4); p3 += __shfl_xor(p3, 4);
        p0 += __shfl_xor(p0, 8); p1 += __shfl_xor(p1, 8); p2 += __shfl_xor(p2, 8); p3 += __shfl_xor(p3, 8);
        if (cnt < 2) p1 = -INFINITY;
        if (cnt < 3) p2 = -INFINITY;
        if (cnt < 4) p3 = -INFINITY;
        float mn = fmaxf(m, fmaxf(fmaxf(p0, p1), fmaxf(p2, p3)));
        float sc = __expf(m - mn);
        float w0 = __expf(p0 - mn), w1 = __expf(p1 - mn);
        float w2 = __expf(p2 - mn), w3 = __expf(p3 - mn);
        l = l * sc + w0 + w1 + w2 + w3;
        acc.x = acc.x * sc + w0 * r0.x + w1 * r1.x + w2 * r2.x + w3 * r3.x;
        acc.y = acc.y * sc + w0 * r0.y + w1 * r1.y + w2 * r2.y + w3 * r3.y;
        acc.z = acc.z * sc + w0 * r0.z + w1 * r1.z + w2 * r2.z + w3 * r3.z;
        acc.w = acc.w * sc + w0 * r0.w + w1 * r1.w + w2 * r2.w + w3 * r3.w;
        m = mn;
    }
    float inv = 1.f / (l + 1e-16f);
    float4 b4 = ((const float4*)bias)[lane];
    float4 o;
    o.x = elu(acc.x * inv + b4.x);
    o.y = elu(acc.y * inv + b4.y);
    o.z = elu(acc.z * inv + b4.z);
    o.w = elu(acc.w * inv + b4.w);
    stbf4(hout + (size_t)i * CH, lane, o);
}

// ---------------- Fused GATv2 layer 2 (bf16 in, fp32 out), 4-edge batched ----------------
__global__ void fused_gat2(const unsigned short* __restrict__ xl, const unsigned short* __restrict__ xr,
                           const int* __restrict__ rowptr, const int* __restrict__ csr,
                           const float* __restrict__ att, const float* __restrict__ bias,
                           float* __restrict__ out, int n) {
    int wid = threadIdx.x >> 6;
    int lane = threadIdx.x & 63;
    int i = blockIdx.x * 4 + wid;
    if (i >= n) return;
    float4 xr4 = ldbf4(xr + (size_t)i * CH, lane);
    float4 a4  = ((const float4*)att)[lane];
    float4 xli = ldbf4(xl + (size_t)i * CH, lane);
    float ps = lrelu(xli.x + xr4.x) * a4.x + lrelu(xli.y + xr4.y) * a4.y +
               lrelu(xli.z + xr4.z) * a4.z + lrelu(xli.w + xr4.w) * a4.w;
    ps += __shfl_xor(ps, 1); ps += __shfl_xor(ps, 2); ps += __shfl_xor(ps, 4);
    ps += __shfl_xor(ps, 8); ps += __shfl_xor(ps, 16); ps += __shfl_xor(ps, 32);
    float m = ps, l = 1.f;
    float4 acc = xli;
    int beg = rowptr[i], end = rowptr[i + 1];
    for (int e = beg; e < end; e += 4) {
        int cnt = end - e;
        int s0 = csr[e];
        int s1 = (cnt > 1) ? csr[e + 1] : s0;
        int s2 = (cnt > 2) ? csr[e + 2] : s0;
        int s3 = (cnt > 3) ? csr[e + 3] : s0;
        float4 r0 = ldbf4(xl + (size_t)s0 * CH, lane);
        float4 r1 = ldbf4(xl + (size_t)s1 * CH, lane);
        float4 r2 = ldbf4(xl + (size_t)s2 * CH, lane);
        float4 r3 = ldbf4(xl + (size_t)s3 * CH, lane);
        float p0 = lrelu(r0.x + xr4.x) * a4.x + lrelu(r0.y + xr4.y) * a4.y +
                   lrelu(r0.z + xr4.z) * a4.z + lrelu(r0.w + xr4.w) * a4.w;
        float p1 = lrelu(r1.x + xr4.x) * a4.x + lrelu(r1.y + xr4.y) * a4.y +
                   lrelu(r1.z + xr4.z) * a4.z + lrelu(r1.w + xr4.w) * a4.w;
        float p2 = lrelu(r2.x + xr4.x) * a4.x + lrelu(r2.y + xr4.y) * a4.y +
                   lrelu(r2.z + xr4.z) * a4.z + lrelu(r2.w + xr4.w) * a4.w;
        float p3 = lrelu(r3.x + xr4.x) * a4.x + lrelu(r3.y + xr4.y) * a4.y +
                   lrelu(r3.z + xr4.z) * a4.z + lrelu(r3.w + xr4.w) * a4.w;
#pragma unroll
        for (int d = 1; d < 64; d <<= 1) {
            p0 += __shfl_xor(p0, d); p1 += __shfl_xor(p1, d);
            p2 += __shfl_xor(p2, d); p3 += __shfl_xor(p3, d);
        }
        if (cnt < 2) p1 = -INFINITY;
        if (cnt < 3) p2 = -INFINITY;
        if (cnt < 4) p3 = -INFINITY;
        float mn = fmaxf(m, fmaxf(fmaxf(p0, p1), fmaxf(p2, p3)));
        float sc = __expf(m - mn);
        float w0 = __expf(p0 - mn), w1 = __expf(p1 - mn);
        float w2 = __expf(p2 - mn), w3 = __expf(p3 - mn);
        l = l * sc + w0 + w1 + w2 + w3;
        acc.x = acc.x * sc + w0 * r0.x + w1 * r1.x + w2 * r2.x + w3 * r3.x;
        acc.y = acc.y * sc + w0 * r0.y + w1 * r1.y + w2 * r2.y + w3 * r3.y;
        acc.z = acc.z * sc + w0 * r0.z + w1 * r1.z + w2 * r2.z + w3 * r3.z;
        acc.w = acc.w * sc + w0 * r0.w + w1 * r1.w + w2 * r2.w + w3 * r3.w;
        m = mn;
    }
    float inv = 1.f / (l + 1e-16f);
    float4 b4 = ((const float4*)bias)[lane];
    float4 o;
    o.x = acc.x * inv + b4.x;
    o.y = acc.y * inv + b4.y;
    o.z = acc.z * inv + b4.z;
    o.w = acc.w * inv + b4.w;
    ((float4*)(out + (size_t)i * CH))[lane] = o;
}

// ---------------- transpose+convert layer2 weights: Wt[z][n][k] bf16 ----------------
__global__ void wconv(const float* __restrict__ Wl2, const float* __restrict__ Wr2,
                      unsigned short* __restrict__ Wt) {
    int t = blockIdx.x * 256 + threadIdx.x;
    int z = t >> 16;
    int idx = t & 65535;
    int k = idx >> 8, nn = idx & 255;
    const float* W = z ? Wr2 : Wl2;
    Wt[z * 65536 + nn * 256 + k] = f2bf(W[k * 256 + nn]);
}

// ---------------- GEMM2 MFMA: h (M x 256 bf16) @ Wt^T + b -> bf16, two weight mats ----------------
#define LDK 40
__global__ __launch_bounds__(256) void gemm_mfma(
        const unsigned short* __restrict__ A,
        const unsigned short* __restrict__ Wt,
        const float* __restrict__ ba, const float* __restrict__ bb,
        unsigned short* __restrict__ Ca, unsigned short* __restrict__ Cb, int M) {
    const unsigned short* Wz = Wt + (size_t)blockIdx.z * 65536;
    const float* bias = blockIdx.z ? bb : ba;
    unsigned short* C = blockIdx.z ? Cb : Ca;

    __shared__ unsigned short As[128 * LDK];
    __shared__ unsigned short Bs[128 * LDK];

    int m0 = blockIdx.x * 128, n0 = blockIdx.y * 128;
    int tid = threadIdx.x;
    int lane = tid & 63, wid = tid >> 6;
    int wm = wid & 1, wn = wid >> 1;
    int q = lane >> 4, l15 = lane & 15;

    f32x4 acc[4][4];
#pragma unroll
    for (int i = 0; i < 4; ++i)
#pragma unroll
        for (int j = 0; j < 4; ++j) acc[i][j] = (f32x4){0.f, 0.f, 0.f, 0.f};

    int r = tid >> 2;
    int c8 = (tid & 3) * 8;
    const uint4 zero4 = make_uint4(0, 0, 0, 0);

    for (int kb = 0; kb < 8; ++kb) {
        int k0 = kb * 32;
        int ra = m0 + r, rb = m0 + r + 64;
        uint4 va0 = (ra < M) ? *(const uint4*)(A + (size_t)ra * 256 + k0 + c8) : zero4;
        uint4 va1 = (rb < M) ? *(const uint4*)(A + (size_t)rb * 256 + k0 + c8) : zero4;
        uint4 vb0 = *(const uint4*)(Wz + (size_t)(n0 + r) * 256 + k0 + c8);
        uint4 vb1 = *(const uint4*)(Wz + (size_t)(n0 + r + 64) * 256 + k0 + c8);
        __syncthreads();
        *(uint4*)&As[r * LDK + c8] = va0;
        *(uint4*)&As[(r + 64) * LDK + c8] = va1;
        *(uint4*)&Bs[r * LDK + c8] = vb0;
        *(uint4*)&Bs[(r + 64) * LDK + c8] = vb1;
        __syncthreads();

        bf16x8 af[4], bfr[4];
#pragma unroll
        for (int f = 0; f < 4; ++f)
            af[f] = *(const bf16x8*)&As[(wm * 64 + f * 16 + l15) * LDK + q * 8];
#pragma unroll
        for (int f = 0; f < 4; ++f)
            bfr[f] = *(const bf16x8*)&Bs[(wn * 64 + f * 16 + l15) * LDK + q * 8];
#pragma unroll
        for (int i = 0; i < 4; ++i)
#pragma unroll
            for (int j = 0; j < 4; ++j)
                acc[i][j] = __builtin_amdgcn_mfma_f32_16x16x32_bf16(af[i], bfr[j], acc[i][j], 0, 0, 0);
    }

#pragma unroll
    for (int j = 0; j < 4; ++j) {
        int gcol = n0 + wn * 64 + j * 16 + l15;
        float bcol = bias[gcol];
#pragma unroll
        for (int i = 0; i < 4; ++i) {
            int row = m0 + wm * 64 + i * 16 + q * 4;
#pragma unroll
            for (int rr = 0; rr < 4; ++rr) {
                int grow = row + rr;
                if (grow < M)
                    C[(size_t)grow * 256 + gcol] = f2bf(acc[i][j][rr] + bcol);
            }
        }
    }
}

extern "C" void kernel_launch(void* const* d_in, const int* in_sizes, int n_in,
                              void* d_out, int out_size, void* d_ws, size_t ws_size,
                              hipStream_t stream) {
    const float* x    = (const float*)d_in[0];
    const int*   ei   = (const int*)d_in[1];
    const float* Wl1  = (const float*)d_in[2];
    const float* bl1  = (const float*)d_in[3];
    const float* Wr1  = (const float*)d_in[4];
    const float* br1  = (const float*)d_in[5];
    const float* att1 = (const float*)d_in[6];
    const float* bias1= (const float*)d_in[7];
    const float* Wl2  = (const float*)d_in[8];
    const float* bl2  = (const float*)d_in[9];
    const float* Wr2  = (const float*)d_in[10];
    const float* br2  = (const float*)d_in[11];
    const float* att2 = (const float*)d_in[12];
    const float* bias2= (const float*)d_in[13];

    int n = in_sizes[0] / 20;
    int e = in_sizes[1] / 2;
    float* out = (float*)d_out;
    size_t nch = (size_t)n * CH;

    unsigned short* buf0 = (unsigned short*)d_ws;
    unsigned short* buf1 = buf0 + nch;
    unsigned short* hbuf = buf1 + nch;
    unsigned short* wt2  = hbuf + nch;
    int* deg    = (int*)(wt2 + 2 * 65536);
    int* rowptr = deg + n;
    int* cursor = rowptr + n + 1;
    int* bsums  = cursor + n;
    int* csr    = bsums + 64;

    hipMemsetAsync(deg, 0, (size_t)n * sizeof(int), stream);

    gemm1_kernel<<<(n + 63) / 64, 256, 0, stream>>>(x, Wl1, bl1, Wr1, br1, buf0, buf1, n);

    count_deg<<<(e + 255) / 256, 256, 0, stream>>>(ei, deg, e);
    int nb = (n + SCAN_BLOCK - 1) / SCAN_BLOCK;
    scan_block_k<<<nb, SCAN_BLOCK, 0, stream>>>(deg, rowptr, bsums, n);
    scan_tops_k<<<1, 64, 0, stream>>>(bsums, nb);
    scan_fix_k<<<nb, SCAN_BLOCK, 0, stream>>>(rowptr, cursor, deg, bsums, n);
    scatter_k<<<(e + 255) / 256, 256, 0, stream>>>(ei, cursor, csr, e);

    wconv<<<512, 256, 0, stream>>>(Wl2, Wr2, wt2);

    fused_gat1<<<(n + 3) / 4, 256, 0, stream>>>(buf0, buf1, rowptr, csr, att1, bias1, hbuf, n);

    gemm_mfma<<<dim3((n + 127) / 128, 2, 2), 256, 0, stream>>>(hbuf, wt2, bl2, br2, buf0, buf1, n);

    fused_gat2<<<(n + 3) / 4, 256, 0, stream>>>(buf0, buf1, rowptr, csr, att2, bias2, out, n);
}